// Round 7
// baseline (59.925 us; speedup 1.0000x reference)
//
#include <hip/hip_runtime.h>
#include <math.h>

#define B_ 32
#define L_ 2048
#define D_ 1024
#define C_ 1024
#define CSPLIT 16
#define WROWS 8            // rows per wave in fused kernel
#define NWAVE 8            // waves per fused block
#define BROWS 64           // rows per block (8 waves x 8 rows)
#define NCH (L_ / BROWS)   // 32 chunks per batch row

// ws float offsets:
//   cb    : [B_]              32768    (32)
//   energ : [B_, L_]          32800    (65536)
//   vpart : [CSPLIT, B_, D_]  98336    (524288)
//   pm    : [B_, NCH]         622624   (1024)
//   ps    : [B_, NCH]         623648   (1024)
//   pc    : [B_, NCH, D_]     624672   (1048576)

// ---- K1: vpart[cc][b][d] = sum_{c in chunk} q[b,c] * W[c,d]; block(0,0) also cb ----
__global__ __launch_bounds__(256) void k_vpart(const float* __restrict__ q,
                                               const float* __restrict__ W,
                                               const float* __restrict__ bh,
                                               float* __restrict__ vpart,
                                               float* __restrict__ cb) {
    int cc = blockIdx.x, dc = blockIdx.y;
    int t  = threadIdx.x;
    __shared__ float qs[B_][65];                 // padded: no bank conflicts
    #pragma unroll
    for (int i = 0; i < 8; ++i) {
        int idx = t + i * 256;                   // 2048 = 32*64
        int b = idx >> 6, cl = idx & 63;
        qs[b][cl] = q[b * C_ + cc * 64 + cl];
    }
    __syncthreads();

    int dl4 = t & 15;
    int bg  = t >> 4;
    float4 a0 = {0,0,0,0}, a1 = {0,0,0,0};
    const float4* W4 = reinterpret_cast<const float4*>(W);
    for (int c = 0; c < 64; ++c) {
        float4 w = W4[(size_t)(cc * 64 + c) * (D_ / 4) + dc * 16 + dl4];
        float q0 = qs[bg * 2 + 0][c];
        float q1 = qs[bg * 2 + 1][c];
        a0.x = fmaf(q0, w.x, a0.x); a0.y = fmaf(q0, w.y, a0.y);
        a0.z = fmaf(q0, w.z, a0.z); a0.w = fmaf(q0, w.w, a0.w);
        a1.x = fmaf(q1, w.x, a1.x); a1.y = fmaf(q1, w.y, a1.y);
        a1.z = fmaf(q1, w.z, a1.z); a1.w = fmaf(q1, w.w, a1.w);
    }
    size_t base = ((size_t)cc * B_ + bg * 2) * D_ + dc * 64 + dl4 * 4;
    *reinterpret_cast<float4*>(vpart + base)      = a0;
    *reinterpret_cast<float4*>(vpart + base + D_) = a1;

    if (cc == 0 && dc == 0) {                    // cb[b] = dot(b_h, q[b])
        int b = t >> 3, l8 = t & 7;
        float s = 0.f;
        for (int c = l8; c < C_; c += 8) s = fmaf(bh[c], q[b * C_ + c], s);
        s += __shfl_xor(s, 4); s += __shfl_xor(s, 2); s += __shfl_xor(s, 1);
        if (l8 == 0) cb[b] = s;
    }
}

// ---- K2 fused: prologue reduces vpart->LDS; then one seq pass w/ online softmax ----
__global__ __launch_bounds__(512) void k_fused(const float* __restrict__ seq,
                                               const float* __restrict__ vpart,
                                               const float* __restrict__ cb,
                                               const int* __restrict__ lenp,
                                               float* __restrict__ energ,
                                               float* __restrict__ pm,
                                               float* __restrict__ ps,
                                               float* __restrict__ pc) {
    int b  = blockIdx.y;
    int ch = blockIdx.x;
    int len = lenp[b];
    int l0 = ch * BROWS;
    if (l0 >= len) return;                       // block-uniform; partial never read
    int t = threadIdx.x, wid = t >> 6, lane = t & 63;
    int lw0 = l0 + wid * WROWS;

    __shared__ float vsm[D_];                    // 4 KB: reduced v[b,:]
    __shared__ float e_sm[BROWS];
    __shared__ float lm[NWAVE], ls[NWAVE];
    __shared__ float lc[NWAVE][D_];              // 32 KB

    // prologue: v[b,d] = sum_cc vpart[cc][b][d]  (2 d's per thread)
    {
        int d2 = t * 2;
        float r0 = 0.f, r1 = 0.f;
        #pragma unroll
        for (int cc = 0; cc < CSPLIT; ++cc) {
            float2 p = *reinterpret_cast<const float2*>(
                vpart + ((size_t)cc * B_ + b) * D_ + d2);
            r0 += p.x; r1 += p.y;
        }
        vsm[d2] = r0; vsm[d2 + 1] = r1;
    }
    __syncthreads();

    float4 v0 = *reinterpret_cast<const float4*>(&vsm[      lane * 4]);
    float4 v1 = *reinterpret_cast<const float4*>(&vsm[256 + lane * 4]);
    float4 v2 = *reinterpret_cast<const float4*>(&vsm[512 + lane * 4]);
    float4 v3 = *reinterpret_cast<const float4*>(&vsm[768 + lane * 4]);
    float cbb = cb[b];

    float m = -INFINITY, s = 0.f;
    float c[16];
    #pragma unroll
    for (int i = 0; i < 16; ++i) c[i] = 0.f;

    if (lw0 < len) {
        #pragma unroll
        for (int r = 0; r < WROWS; ++r) {
            int l = lw0 + r;
            if (l >= len) break;                 // wave-uniform
            const float* row = seq + ((size_t)b * L_ + l) * D_;
            float4 s0 = *reinterpret_cast<const float4*>(row +       lane * 4);
            float4 s1 = *reinterpret_cast<const float4*>(row + 256 + lane * 4);
            float4 s2 = *reinterpret_cast<const float4*>(row + 512 + lane * 4);
            float4 s3 = *reinterpret_cast<const float4*>(row + 768 + lane * 4);
            float ac0 = 0.f, ac1 = 0.f, ac2 = 0.f, ac3 = 0.f;   // 4 indep chains
            ac0 = fmaf(s0.x, v0.x, ac0); ac0 = fmaf(s0.y, v0.y, ac0);
            ac0 = fmaf(s0.z, v0.z, ac0); ac0 = fmaf(s0.w, v0.w, ac0);
            ac1 = fmaf(s1.x, v1.x, ac1); ac1 = fmaf(s1.y, v1.y, ac1);
            ac1 = fmaf(s1.z, v1.z, ac1); ac1 = fmaf(s1.w, v1.w, ac1);
            ac2 = fmaf(s2.x, v2.x, ac2); ac2 = fmaf(s2.y, v2.y, ac2);
            ac2 = fmaf(s2.z, v2.z, ac2); ac2 = fmaf(s2.w, v2.w, ac2);
            ac3 = fmaf(s3.x, v3.x, ac3); ac3 = fmaf(s3.y, v3.y, ac3);
            ac3 = fmaf(s3.z, v3.z, ac3); ac3 = fmaf(s3.w, v3.w, ac3);
            float acc = (ac0 + ac1) + (ac2 + ac3);
            #pragma unroll
            for (int off = 32; off; off >>= 1) acc += __shfl_xor(acc, off);
            float e = acc + cbb;                 // wave-uniform after butterfly
            if (lane == 0) e_sm[wid * WROWS + r] = e;
            if (e > m) {                         // wave-uniform, rare (~H(8))
                float sc = __expf(m - e);        // first row: exp(-inf)=0
                s = fmaf(s, sc, 1.f);
                c[ 0] = fmaf(c[ 0], sc, s0.x); c[ 1] = fmaf(c[ 1], sc, s0.y);
                c[ 2] = fmaf(c[ 2], sc, s0.z); c[ 3] = fmaf(c[ 3], sc, s0.w);
                c[ 4] = fmaf(c[ 4], sc, s1.x); c[ 5] = fmaf(c[ 5], sc, s1.y);
                c[ 6] = fmaf(c[ 6], sc, s1.z); c[ 7] = fmaf(c[ 7], sc, s1.w);
                c[ 8] = fmaf(c[ 8], sc, s2.x); c[ 9] = fmaf(c[ 9], sc, s2.y);
                c[10] = fmaf(c[10], sc, s2.z); c[11] = fmaf(c[11], sc, s2.w);
                c[12] = fmaf(c[12], sc, s3.x); c[13] = fmaf(c[13], sc, s3.y);
                c[14] = fmaf(c[14], sc, s3.z); c[15] = fmaf(c[15], sc, s3.w);
                m = e;
            } else {                             // common path: no rescale
                float p = __expf(e - m);
                s += p;
                c[ 0] = fmaf(p, s0.x, c[ 0]); c[ 1] = fmaf(p, s0.y, c[ 1]);
                c[ 2] = fmaf(p, s0.z, c[ 2]); c[ 3] = fmaf(p, s0.w, c[ 3]);
                c[ 4] = fmaf(p, s1.x, c[ 4]); c[ 5] = fmaf(p, s1.y, c[ 5]);
                c[ 6] = fmaf(p, s1.z, c[ 6]); c[ 7] = fmaf(p, s1.w, c[ 7]);
                c[ 8] = fmaf(p, s2.x, c[ 8]); c[ 9] = fmaf(p, s2.y, c[ 9]);
                c[10] = fmaf(p, s2.z, c[10]); c[11] = fmaf(p, s2.w, c[11]);
                c[12] = fmaf(p, s3.x, c[12]); c[13] = fmaf(p, s3.y, c[13]);
                c[14] = fmaf(p, s3.z, c[14]); c[15] = fmaf(p, s3.w, c[15]);
            }
        }
    }

    {
        float4 w0 = {c[ 0], c[ 1], c[ 2], c[ 3]};
        float4 w1 = {c[ 4], c[ 5], c[ 6], c[ 7]};
        float4 w2 = {c[ 8], c[ 9], c[10], c[11]};
        float4 w3 = {c[12], c[13], c[14], c[15]};
        *reinterpret_cast<float4*>(&lc[wid][      lane * 4]) = w0;
        *reinterpret_cast<float4*>(&lc[wid][256 + lane * 4]) = w1;
        *reinterpret_cast<float4*>(&lc[wid][512 + lane * 4]) = w2;
        *reinterpret_cast<float4*>(&lc[wid][768 + lane * 4]) = w3;
        if (lane == 0) { lm[wid] = m; ls[wid] = s; }
    }
    __syncthreads();

    if (t < BROWS) energ[(size_t)b * L_ + l0 + t] = e_sm[t];

    float mb = lm[0];
    #pragma unroll
    for (int i = 1; i < NWAVE; ++i) mb = fmaxf(mb, lm[i]);
    float wgt[NWAVE], sb = 0.f;
    #pragma unroll
    for (int i = 0; i < NWAVE; ++i) {
        wgt[i] = (lm[i] == mb) ? 1.f : __expf(lm[i] - mb);
        sb = fmaf(wgt[i], ls[i], sb);
    }

    float ox = 0.f, oy = 0.f;
    #pragma unroll
    for (int i = 0; i < NWAVE; ++i) {
        ox = fmaf(wgt[i], lc[i][t * 2],     ox);
        oy = fmaf(wgt[i], lc[i][t * 2 + 1], oy);
    }
    size_t pidx = (size_t)b * NCH + ch;
    if (t == 0) { pm[pidx] = mb; ps[pidx] = sb; }
    float2 o2 = {ox, oy};
    *reinterpret_cast<float2*>(pc + pidx * D_ + t * 2) = o2;
}

// ---- K3: per-(b, slice) final merge -> contexts + scores. 256 blocks. ----
__global__ __launch_bounds__(256) void k_final(const float* __restrict__ pm,
                                               const float* __restrict__ ps,
                                               const float* __restrict__ pc,
                                               const float* __restrict__ energ,
                                               const int* __restrict__ lenp,
                                               float* __restrict__ ctx,
                                               float* __restrict__ scores) {
    int b = blockIdx.x, sl = blockIdx.y, t = threadIdx.x;
    int len = lenp[b];
    int nch = (len + BROWS - 1) / BROWS;         // 1..32
    __shared__ float wgt[NCH];
    __shared__ float Msh, Ssh;
    if (t < 64) {
        float mi = (t < nch) ? pm[(size_t)b * NCH + t] : -INFINITY;
        float si = (t < nch) ? ps[(size_t)b * NCH + t] : 0.f;
        float M = mi;
        #pragma unroll
        for (int off = 32; off; off >>= 1) M = fmaxf(M, __shfl_xor(M, off));
        float ew = (t < nch) ? __expf(mi - M) : 0.f;
        float S  = ew * si;
        #pragma unroll
        for (int off = 32; off; off >>= 1) S += __shfl_xor(S, off);
        if (t < nch) wgt[t] = ew / S;
        if (t == 0) { Msh = M; Ssh = S; }
    }
    __syncthreads();
    float M = Msh;
    float invS = 1.f / Ssh;

    if (t < 128) {                               // context slice: 128 d's
        int d = sl * 128 + t;
        float o = 0.f;
        for (int ch = 0; ch < nch; ++ch)
            o = fmaf(wgt[ch], pc[((size_t)b * NCH + ch) * D_ + d], o);
        ctx[(size_t)b * D_ + d] = o;
    }

    int l = sl * 256 + t;                        // scores slice: 256 l's
    float e = energ[(size_t)b * L_ + l];
    scores[(size_t)b * L_ + l] = (l < len) ? __expf(e - M) * invS : 0.f;
}

extern "C" void kernel_launch(void* const* d_in, const int* in_sizes, int n_in,
                              void* d_out, int out_size, void* d_ws, size_t ws_size,
                              hipStream_t stream) {
    const float* seq     = (const float*)d_in[0];   // [B,L,D]
    const float* query   = (const float*)d_in[1];   // [B,C]
    const int*   lengths = (const int*)  d_in[2];   // [B]
    const float* W_h     = (const float*)d_in[3];   // [C,D]
    const float* b_h     = (const float*)d_in[4];   // [C]

    float* out    = (float*)d_out;
    float* ctx    = out;                 // [B,D]
    float* scores = out + B_ * D_;       // [B,L]

    float* ws    = (float*)d_ws;
    float* cb    = ws + 32768;
    float* energ = ws + 32800;
    float* vpart = ws + 98336;
    float* pm    = ws + 622624;
    float* ps    = ws + 623648;
    float* pc    = ws + 624672;

    k_vpart<<<dim3(16, 16), 256, 0, stream>>>(query, W_h, b_h, vpart, cb);
    k_fused<<<dim3(NCH, B_), 512, 0, stream>>>(seq, vpart, cb, lengths, energ, pm, ps, pc);
    k_final<<<dim3(B_, 8), 256, 0, stream>>>(pm, ps, pc, energ, lengths, ctx, scores);
}

// Round 8
// 45.642 us; speedup vs baseline: 1.3129x; 1.3129x over previous
//
#include <hip/hip_runtime.h>
#include <math.h>

#define B_ 32
#define L_ 2048
#define D_ 1024
#define C_ 1024
#define CSPLIT 16
#define WROWS 8            // rows per wave in fused kernel
#define NWAVE 8            // waves per fused block
#define BROWS 64           // rows per block (8 waves x 8 rows)
#define NCH (L_ / BROWS)   // 32 chunks per batch row

// ws float offsets:
//   v     : [B_, D_]          0        (32768)
//   cb    : [B_]              32768    (32)
//   energ : [B_, L_]          32800    (65536)
//   vpart : [CSPLIT, B_, D_]  98336    (524288)
//   pm    : [B_, NCH]         622624   (1024)
//   ps    : [B_, NCH]         623648   (1024)
//   pc    : [B_, NCH, D_]     624672   (1048576)

// ---- K1a: vpart[cc][b][d] = sum_{c in cc-chunk} q[b,c] * W[c,d] ----
__global__ __launch_bounds__(256) void k_vpart(const float* __restrict__ q,
                                               const float* __restrict__ W,
                                               float* __restrict__ vpart) {
    int cc = blockIdx.x, dc = blockIdx.y;
    int t  = threadIdx.x;
    __shared__ float qs[B_][65];                 // padded: no bank conflicts
    #pragma unroll
    for (int i = 0; i < 8; ++i) {
        int idx = t + i * 256;                   // 2048 = 32*64
        int b = idx >> 6, cl = idx & 63;
        qs[b][cl] = q[b * C_ + cc * 64 + cl];
    }
    __syncthreads();

    int dl4 = t & 15;
    int bg  = t >> 4;
    float4 a0 = {0,0,0,0}, a1 = {0,0,0,0};
    const float4* W4 = reinterpret_cast<const float4*>(W);
    for (int c = 0; c < 64; ++c) {
        float4 w = W4[(size_t)(cc * 64 + c) * (D_ / 4) + dc * 16 + dl4];
        float q0 = qs[bg * 2 + 0][c];
        float q1 = qs[bg * 2 + 1][c];
        a0.x = fmaf(q0, w.x, a0.x); a0.y = fmaf(q0, w.y, a0.y);
        a0.z = fmaf(q0, w.z, a0.z); a0.w = fmaf(q0, w.w, a0.w);
        a1.x = fmaf(q1, w.x, a1.x); a1.y = fmaf(q1, w.y, a1.y);
        a1.z = fmaf(q1, w.z, a1.z); a1.w = fmaf(q1, w.w, a1.w);
    }
    size_t base = ((size_t)cc * B_ + bg * 2) * D_ + dc * 64 + dl4 * 4;
    *reinterpret_cast<float4*>(vpart + base)      = a0;
    *reinterpret_cast<float4*>(vpart + base + D_) = a1;
}

// ---- K1b: reduce vpart -> v;  cb[b] = dot(b_h, query[b]) ----
__global__ __launch_bounds__(256) void k_vreduce(const float* __restrict__ vpart,
                                                 float* __restrict__ v,
                                                 const float* __restrict__ q,
                                                 const float* __restrict__ bh,
                                                 float* __restrict__ cb) {
    int b = blockIdx.x, dq = blockIdx.y, t = threadIdx.x;
    int d = dq * 256 + t;
    float a = 0.f;
    #pragma unroll
    for (int cc = 0; cc < CSPLIT; ++cc)
        a += vpart[((size_t)cc * B_ + b) * D_ + d];
    v[(size_t)b * D_ + d] = a;

    if (dq == 0) {
        float s = 0.f;
        for (int c = t; c < C_; c += 256) s += bh[c] * q[b * C_ + c];
        __shared__ float red[256];
        red[t] = s; __syncthreads();
        for (int off = 128; off > 0; off >>= 1) {
            if (t < off) red[t] += red[t + off];
            __syncthreads();
        }
        if (t == 0) cb[b] = red[0];
    }
}

// ---- K2 fused: depth-1 prefetched row loop; deferred-rescale online softmax ----
__global__ __launch_bounds__(512) void k_fused(const float* __restrict__ seq,
                                               const float* __restrict__ v,
                                               const float* __restrict__ cb,
                                               const int* __restrict__ lenp,
                                               float* __restrict__ energ,
                                               float* __restrict__ pm,
                                               float* __restrict__ ps,
                                               float* __restrict__ pc) {
    int b  = blockIdx.y;
    int ch = blockIdx.x;
    int len = lenp[b];
    int l0 = ch * BROWS;
    if (l0 >= len) return;                       // partial never read downstream
    int t = threadIdx.x, wid = t >> 6, lane = t & 63;
    int lw0 = l0 + wid * WROWS;

    const float* vb = v + (size_t)b * D_;
    float4 v0 = *reinterpret_cast<const float4*>(vb +       lane * 4);
    float4 v1 = *reinterpret_cast<const float4*>(vb + 256 + lane * 4);
    float4 v2 = *reinterpret_cast<const float4*>(vb + 512 + lane * 4);
    float4 v3 = *reinterpret_cast<const float4*>(vb + 768 + lane * 4);
    float cbb = cb[b];

    float m = -INFINITY, s = 0.f;
    float c[16];
    #pragma unroll
    for (int i = 0; i < 16; ++i) c[i] = 0.f;

    __shared__ float e_sm[BROWS];
    __shared__ float lm[NWAVE], ls[NWAVE];
    __shared__ float lc[NWAVE][D_];              // 32 KB

    // process one loaded row: dot -> butterfly -> deferred-rescale update
    auto process = [&](const float4& s0, const float4& s1,
                       const float4& s2, const float4& s3, int r) {
        float ac0 = 0.f, ac1 = 0.f, ac2 = 0.f, ac3 = 0.f;
        ac0 = fmaf(s0.x, v0.x, ac0); ac0 = fmaf(s0.y, v0.y, ac0);
        ac0 = fmaf(s0.z, v0.z, ac0); ac0 = fmaf(s0.w, v0.w, ac0);
        ac1 = fmaf(s1.x, v1.x, ac1); ac1 = fmaf(s1.y, v1.y, ac1);
        ac1 = fmaf(s1.z, v1.z, ac1); ac1 = fmaf(s1.w, v1.w, ac1);
        ac2 = fmaf(s2.x, v2.x, ac2); ac2 = fmaf(s2.y, v2.y, ac2);
        ac2 = fmaf(s2.z, v2.z, ac2); ac2 = fmaf(s2.w, v2.w, ac2);
        ac3 = fmaf(s3.x, v3.x, ac3); ac3 = fmaf(s3.y, v3.y, ac3);
        ac3 = fmaf(s3.z, v3.z, ac3); ac3 = fmaf(s3.w, v3.w, ac3);
        float acc = (ac0 + ac1) + (ac2 + ac3);
        #pragma unroll
        for (int off = 32; off; off >>= 1) acc += __shfl_xor(acc, off);
        float e = acc + cbb;                     // wave-uniform after butterfly
        if (lane == 0) e_sm[wid * WROWS + r] = e;
        if (e > m) {                             // wave-uniform, rare (~H(8))
            float sc = __expf(m - e);            // first row: exp(-inf)=0
            s = fmaf(s, sc, 1.f);
            c[ 0] = fmaf(c[ 0], sc, s0.x); c[ 1] = fmaf(c[ 1], sc, s0.y);
            c[ 2] = fmaf(c[ 2], sc, s0.z); c[ 3] = fmaf(c[ 3], sc, s0.w);
            c[ 4] = fmaf(c[ 4], sc, s1.x); c[ 5] = fmaf(c[ 5], sc, s1.y);
            c[ 6] = fmaf(c[ 6], sc, s1.z); c[ 7] = fmaf(c[ 7], sc, s1.w);
            c[ 8] = fmaf(c[ 8], sc, s2.x); c[ 9] = fmaf(c[ 9], sc, s2.y);
            c[10] = fmaf(c[10], sc, s2.z); c[11] = fmaf(c[11], sc, s2.w);
            c[12] = fmaf(c[12], sc, s3.x); c[13] = fmaf(c[13], sc, s3.y);
            c[14] = fmaf(c[14], sc, s3.z); c[15] = fmaf(c[15], sc, s3.w);
            m = e;
        } else {                                 // common path: no rescale
            float p = __expf(e - m);
            s += p;
            c[ 0] = fmaf(p, s0.x, c[ 0]); c[ 1] = fmaf(p, s0.y, c[ 1]);
            c[ 2] = fmaf(p, s0.z, c[ 2]); c[ 3] = fmaf(p, s0.w, c[ 3]);
            c[ 4] = fmaf(p, s1.x, c[ 4]); c[ 5] = fmaf(p, s1.y, c[ 5]);
            c[ 6] = fmaf(p, s1.z, c[ 6]); c[ 7] = fmaf(p, s1.w, c[ 7]);
            c[ 8] = fmaf(p, s2.x, c[ 8]); c[ 9] = fmaf(p, s2.y, c[ 9]);
            c[10] = fmaf(p, s2.z, c[10]); c[11] = fmaf(p, s2.w, c[11]);
            c[12] = fmaf(p, s3.x, c[12]); c[13] = fmaf(p, s3.y, c[13]);
            c[14] = fmaf(p, s3.z, c[14]); c[15] = fmaf(p, s3.w, c[15]);
        }
    };

    int nr = (lw0 < len) ? min(WROWS, len - lw0) : 0;   // wave-uniform
    if (nr > 0) {
        const float* rowp = seq + ((size_t)b * L_ + lw0) * D_;
        float4 cs0 = *reinterpret_cast<const float4*>(rowp +       lane * 4);
        float4 cs1 = *reinterpret_cast<const float4*>(rowp + 256 + lane * 4);
        float4 cs2 = *reinterpret_cast<const float4*>(rowp + 512 + lane * 4);
        float4 cs3 = *reinterpret_cast<const float4*>(rowp + 768 + lane * 4);
        for (int r = 0; r < nr - 1; ++r) {
            const float* nrow = rowp + (size_t)(r + 1) * D_;
            float4 ns0 = *reinterpret_cast<const float4*>(nrow +       lane * 4);
            float4 ns1 = *reinterpret_cast<const float4*>(nrow + 256 + lane * 4);
            float4 ns2 = *reinterpret_cast<const float4*>(nrow + 512 + lane * 4);
            float4 ns3 = *reinterpret_cast<const float4*>(nrow + 768 + lane * 4);
            process(cs0, cs1, cs2, cs3, r);
            cs0 = ns0; cs1 = ns1; cs2 = ns2; cs3 = ns3;
        }
        process(cs0, cs1, cs2, cs3, nr - 1);
    }

    {
        float4 w0 = {c[ 0], c[ 1], c[ 2], c[ 3]};
        float4 w1 = {c[ 4], c[ 5], c[ 6], c[ 7]};
        float4 w2 = {c[ 8], c[ 9], c[10], c[11]};
        float4 w3 = {c[12], c[13], c[14], c[15]};
        *reinterpret_cast<float4*>(&lc[wid][      lane * 4]) = w0;
        *reinterpret_cast<float4*>(&lc[wid][256 + lane * 4]) = w1;
        *reinterpret_cast<float4*>(&lc[wid][512 + lane * 4]) = w2;
        *reinterpret_cast<float4*>(&lc[wid][768 + lane * 4]) = w3;
        if (lane == 0) { lm[wid] = m; ls[wid] = s; }
    }
    __syncthreads();

    if (t < BROWS) energ[(size_t)b * L_ + l0 + t] = e_sm[t];

    // 8-way combine (weights wave-uniform; empty waves have lm=-inf -> w=0)
    float mb = lm[0];
    #pragma unroll
    for (int i = 1; i < NWAVE; ++i) mb = fmaxf(mb, lm[i]);
    float wgt[NWAVE], sb = 0.f;
    #pragma unroll
    for (int i = 0; i < NWAVE; ++i) {
        wgt[i] = (lm[i] == mb) ? 1.f : __expf(lm[i] - mb);
        sb = fmaf(wgt[i], ls[i], sb);
    }

    float ox = 0.f, oy = 0.f;
    #pragma unroll
    for (int i = 0; i < NWAVE; ++i) {
        ox = fmaf(wgt[i], lc[i][t * 2],     ox);
        oy = fmaf(wgt[i], lc[i][t * 2 + 1], oy);
    }
    size_t pidx = (size_t)b * NCH + ch;
    if (t == 0) { pm[pidx] = mb; ps[pidx] = sb; }
    float2 o2 = {ox, oy};
    *reinterpret_cast<float2*>(pc + pidx * D_ + t * 2) = o2;
}

// ---- K3: per-(b, slice) final merge -> contexts + scores. 256 blocks. ----
__global__ __launch_bounds__(256) void k_final(const float* __restrict__ pm,
                                               const float* __restrict__ ps,
                                               const float* __restrict__ pc,
                                               const float* __restrict__ energ,
                                               const int* __restrict__ lenp,
                                               float* __restrict__ ctx,
                                               float* __restrict__ scores) {
    int b = blockIdx.x, sl = blockIdx.y, t = threadIdx.x;
    int len = lenp[b];
    int nch = (len + BROWS - 1) / BROWS;         // 1..32
    __shared__ float wgt[NCH];
    __shared__ float Msh, Ssh;
    if (t < 64) {
        float mi = (t < nch) ? pm[(size_t)b * NCH + t] : -INFINITY;
        float si = (t < nch) ? ps[(size_t)b * NCH + t] : 0.f;
        float M = mi;
        #pragma unroll
        for (int off = 32; off; off >>= 1) M = fmaxf(M, __shfl_xor(M, off));
        float ew = (t < nch) ? __expf(mi - M) : 0.f;
        float S  = ew * si;
        #pragma unroll
        for (int off = 32; off; off >>= 1) S += __shfl_xor(S, off);
        if (t < nch) wgt[t] = ew / S;
        if (t == 0) { Msh = M; Ssh = S; }
    }
    __syncthreads();
    float M = Msh;
    float invS = 1.f / Ssh;

    if (t < 128) {                               // context slice: 128 d's
        int d = sl * 128 + t;
        float o = 0.f;
        for (int ch = 0; ch < nch; ++ch)
            o = fmaf(wgt[ch], pc[((size_t)b * NCH + ch) * D_ + d], o);
        ctx[(size_t)b * D_ + d] = o;
    }

    int l = sl * 256 + t;                        // scores slice: 256 l's
    float e = energ[(size_t)b * L_ + l];
    scores[(size_t)b * L_ + l] = (l < len) ? __expf(e - M) * invS : 0.f;
}

extern "C" void kernel_launch(void* const* d_in, const int* in_sizes, int n_in,
                              void* d_out, int out_size, void* d_ws, size_t ws_size,
                              hipStream_t stream) {
    const float* seq     = (const float*)d_in[0];   // [B,L,D]
    const float* query   = (const float*)d_in[1];   // [B,C]
    const int*   lengths = (const int*)  d_in[2];   // [B]
    const float* W_h     = (const float*)d_in[3];   // [C,D]
    const float* b_h     = (const float*)d_in[4];   // [C]

    float* out    = (float*)d_out;
    float* ctx    = out;                 // [B,D]
    float* scores = out + B_ * D_;       // [B,L]

    float* ws    = (float*)d_ws;
    float* v     = ws;
    float* cb    = ws + 32768;
    float* energ = ws + 32800;
    float* vpart = ws + 98336;
    float* pm    = ws + 622624;
    float* ps    = ws + 623648;
    float* pc    = ws + 624672;

    k_vpart  <<<dim3(16, 16), 256, 0, stream>>>(query, W_h, vpart);
    k_vreduce<<<dim3(B_, 4), 256, 0, stream>>>(vpart, v, query, b_h, cb);
    k_fused  <<<dim3(NCH, B_), 512, 0, stream>>>(seq, v, cb, lengths, energ, pm, ps, pc);
    k_final  <<<dim3(B_, 8), 256, 0, stream>>>(pm, ps, pc, energ, lengths, ctx, scores);
}